// Round 8
// baseline (113.149 us; speedup 1.0000x reference)
//
#include <hip/hip_runtime.h>
#include <hip/hip_bf16.h>
#include <stdint.h>

// Problem constants
#define M_TOK 16384   // B*S = 8*2048
#define E_DIM 768
#define FF_DIM 3072
#define Q_N 8

typedef __attribute__((ext_vector_type(8))) short bf16x8;
typedef __attribute__((ext_vector_type(4))) float f32x4;

__device__ inline unsigned short f2bf(float f) {
  union { float f; unsigned u; } v; v.f = f;
  unsigned r = v.u + 0x7fffu + ((v.u >> 16) & 1u);  // round-to-nearest-even
  return (unsigned short)(r >> 16);
}

// ---------------- kernel 0: w2 fp32 -> bf16 ----------------
__global__ __launch_bounds__(256) void cvt_w2(const float* __restrict__ w2,
                                              __hip_bfloat16* __restrict__ w2b) {
  int i = (blockIdx.x * 256 + threadIdx.x) * 4;
  const int n = E_DIM * FF_DIM;
  if (i < n) {
    float4 v = *(const float4*)(w2 + i);
    ushort4 o;
    o.x = f2bf(v.x); o.y = f2bf(v.y); o.z = f2bf(v.z); o.w = f2bf(v.w);
    *(ushort4*)((unsigned short*)w2b + i) = o;
  }
}

// ---------------- kernel 1: h = relu(cos(x[:, :8]+phi) @ w1^T + b1), bf16 ----
__global__ __launch_bounds__(256) void compute_h(const float* __restrict__ x,
                                                 const float* __restrict__ phi,
                                                 const float* __restrict__ w1,
                                                 const float* __restrict__ b1,
                                                 __hip_bfloat16* __restrict__ hout) {
  __shared__ float s_meas[32][8];
  const int t = threadIdx.x;
  const int bm = blockIdx.x / 6;
  const int bf = blockIdx.x % 6;
  const int m0 = bm * 32;
  const int f0 = bf * 512;

  if (t < 64) {
    int m = t >> 1, hh = t & 1;
    float4 v = *(const float4*)(x + (size_t)(m0 + m) * E_DIM + hh * 4);
    float4 p = *(const float4*)(phi + hh * 4);
    s_meas[m][hh * 4 + 0] = __cosf(v.x + p.x);
    s_meas[m][hh * 4 + 1] = __cosf(v.y + p.y);
    s_meas[m][hh * 4 + 2] = __cosf(v.z + p.z);
    s_meas[m][hh * 4 + 3] = __cosf(v.w + p.w);
  }
  __syncthreads();

  const float4* wr = (const float4*)(w1 + (size_t)(f0 + 2 * t) * Q_N);
  float4 a0 = wr[0], a1 = wr[1], b0 = wr[2], b1v = wr[3];
  float wA[8] = {a0.x, a0.y, a0.z, a0.w, a1.x, a1.y, a1.z, a1.w};
  float wB[8] = {b0.x, b0.y, b0.z, b0.w, b1v.x, b1v.y, b1v.z, b1v.w};
  const float biasA = b1[f0 + 2 * t];
  const float biasB = b1[f0 + 2 * t + 1];

  uint32_t* dst32 = (uint32_t*)hout;
  for (int m = 0; m < 32; ++m) {
    float a = biasA, b = biasB;
#pragma unroll
    for (int q = 0; q < 8; ++q) {
      float mv = s_meas[m][q];
      a = fmaf(mv, wA[q], a);
      b = fmaf(mv, wB[q], b);
    }
    a = fmaxf(a, 0.f);
    b = fmaxf(b, 0.f);
    uint32_t pack = (uint32_t)f2bf(a) | ((uint32_t)f2bf(b) << 16);
    dst32[(size_t)(m0 + m) * (FF_DIM / 2) + (f0 / 2) + t] = pack;
  }
}

// ---------------- kernel 2: C[M,N] = h[M,K] @ w2b[N,K]^T + b2 ---------------
// R8: break the ds_read<->MFMA serialization (model fit R0/R4/R5/R7: tile ~
// LDS-read-cycles + MFMA-cycles, serialized by double-buffer timing).
// TRIPLE-buffer LDS (3 x 40KB = 120KB, 1 blk/CU) so buf[t+1] is complete one
// tile early; per tile: STAGE(t+2) | read K1-frags(t) | MFMA-K0 on frags
// prefetched LAST tile (no lgkm dep -> overlaps the reads) | vmcnt(10)+bar
// (retires stage(t+1), stage(t+2) stays in flight = counted T4, depth 2) |
// read K0-frags(t+1) from buf[t+1] | MFMA-K1 | bar.
// Frag sets ping-pong (pa/pb <-> qa/qb), period-6 unroll, static indices.
// BM=128, BN=192, 256 thr, wave tile 64x96 (2Mx2N), acc[4][6]. grid 512.
#define GLDS16(g, l)                                                          \
  __builtin_amdgcn_global_load_lds(                                           \
      (const __attribute__((address_space(1))) void*)(g),                     \
      (__attribute__((address_space(3))) void*)(l), 16, 0, 0)

#define BUF_ELEMS 20480   // (128*64 + 192*64) bf16 elems = 40KB
#define B_OFF 8192        // A region: 128*64 elems

__global__ __launch_bounds__(256, 1) void gemm_bt(const __hip_bfloat16* __restrict__ A,
                                                  const __hip_bfloat16* __restrict__ Bw,
                                                  const float* __restrict__ b2,
                                                  float* __restrict__ C) {
  const int K = FF_DIM;   // 3072
  const int N = E_DIM;    // 768

  __shared__ __align__(16) __hip_bfloat16 lds[3 * BUF_ELEMS];  // 120 KiB

  const int t = threadIdx.x;
  // XCD-aware bijective swizzle: nwg = 512, 512 % 8 == 0.
  // bn-siblings (same bm) land on the same XCD.
  const int swz = (blockIdx.x & 7) * 64 + (blockIdx.x >> 3);
  const int bm = swz >> 2;        // 0..127
  const int bn = swz & 3;         // 0..3
  const size_t m0 = (size_t)bm * 128;
  const int n0 = bn * 192;

  const int w = t >> 6, l = t & 63;
  const int wr = w >> 1;          // 0..1  (M wave row, 64 rows)
  const int wc = w & 1;           // 0..1  (N wave col, 96 cols)
  const int lr = l & 15;
  const int lk = l >> 4;          // 0..3

  // fragment-read swizzled chunk constants: row&7 == lr&7 for all frag rows
  const int x0 = lk ^ (lr & 7);        // k-half 0 chunk
  const int x1 = x0 ^ 4;               // k-half 1 chunk
  const int baseA = (wr * 64 + lr) * 64;
  const int baseB = B_OFF + (wc * 96 + lr) * 64;
  const int offA0 = baseA + x0 * 8, offA1 = baseA + x1 * 8;
  const int offB0 = baseB + x0 * 8, offB1 = baseB + x1 * 8;

  // staging: span = 32 rows x 128B = 4KB = 256 thr x 16B. dest = t*16B linear.
  // row-in-span rs = t>>3 (0..31), phys chunk pc = t&7, logical lc = pc^(rs&7)
  const int rs = t >> 3;
  const int lc = (t & 7) ^ (rs & 7);
  const __hip_bfloat16* sA[4];
  const __hip_bfloat16* sB[6];
#pragma unroll
  for (int s = 0; s < 4; ++s) sA[s] = A + (m0 + s * 32 + rs) * (size_t)K + lc * 8;
#pragma unroll
  for (int s = 0; s < 6; ++s) sB[s] = Bw + ((size_t)n0 + s * 32 + rs) * K + lc * 8;

  f32x4 acc[4][6] = {};

#define STAGE(K0S, WBUF)                                                      \
  {                                                                           \
    __hip_bfloat16* ld = lds + (WBUF) * BUF_ELEMS + t * 8;                    \
    GLDS16(sA[0] + (K0S), ld);                                                \
    GLDS16(sA[1] + (K0S), ld + 2048);                                         \
    GLDS16(sA[2] + (K0S), ld + 4096);                                         \
    GLDS16(sA[3] + (K0S), ld + 6144);                                         \
    GLDS16(sB[0] + (K0S), ld + 8192);                                         \
    GLDS16(sB[1] + (K0S), ld + 10240);                                        \
    GLDS16(sB[2] + (K0S), ld + 12288);                                        \
    GLDS16(sB[3] + (K0S), ld + 14336);                                        \
    GLDS16(sB[4] + (K0S), ld + 16384);                                        \
    GLDS16(sB[5] + (K0S), ld + 18432);                                        \
  }

#define RD_K0(DA, DB, LA)                                                     \
  _Pragma("unroll") for (int mi = 0; mi < 4; ++mi)                            \
      DA[mi] = *(const bf16x8*)((LA) + offA0 + mi * 1024);                    \
  _Pragma("unroll") for (int ni = 0; ni < 6; ++ni)                            \
      DB[ni] = *(const bf16x8*)((LA) + offB0 + ni * 1024);

#define RD_K1(DA, DB, LA)                                                     \
  _Pragma("unroll") for (int mi = 0; mi < 4; ++mi)                            \
      DA[mi] = *(const bf16x8*)((LA) + offA1 + mi * 1024);                    \
  _Pragma("unroll") for (int ni = 0; ni < 6; ++ni)                            \
      DB[ni] = *(const bf16x8*)((LA) + offB1 + ni * 1024);

#define MFMA_BLK(FA, FB)                                                      \
  _Pragma("unroll") for (int mi = 0; mi < 4; ++mi)                            \
    _Pragma("unroll") for (int ni = 0; ni < 6; ++ni)                          \
      acc[mi][ni] = __builtin_amdgcn_mfma_f32_16x16x32_bf16(                  \
          FA[mi], FB[ni], acc[mi][ni], 0, 0, 0);

  // TILE(t): CA/CB = K0 frags of t (prefetched during t-1); NA/NB receive K0
  // frags of t+1. Buffers: cur=t%3, nxt=(t+1)%3, stg=(t+2)%3.
  // Hazards: STAGE writes buf[t+2] (read earliest at t+1 after its vmcnt-ret);
  // K1 reads of buf[t] complete (lgkm) before end barrier, and buf[t] is only
  // rewritten by STAGE in tile t+1 (after that barrier). All counted waits.
#define TILE(KT, RBCUR, RBNXT, RBSTG, CA, CB, NA, NB, DO_STAGE, DO_NEXT)      \
  {                                                                           \
    const __hip_bfloat16* lcur = lds + (RBCUR) * BUF_ELEMS;                   \
    const __hip_bfloat16* lnxt = lds + (RBNXT) * BUF_ELEMS;                   \
    if (DO_STAGE) STAGE(((KT) + 2) * 64, (RBSTG));                            \
    bf16x8 fa1[4], fb1[6];                                                    \
    RD_K1(fa1, fb1, lcur);                                                    \
    __builtin_amdgcn_s_setprio(1);                                            \
    MFMA_BLK(CA, CB);            /* no dep on this tile's ds_reads */         \
    __builtin_amdgcn_s_setprio(0);                                            \
    if (DO_STAGE) { asm volatile("s_waitcnt vmcnt(10)" ::: "memory"); }       \
    else          { asm volatile("s_waitcnt vmcnt(0)"  ::: "memory"); }       \
    __builtin_amdgcn_s_barrier();  /* stage(t+1) now visible to all */        \
    if (DO_NEXT) { RD_K0(NA, NB, lnxt); }                                     \
    __builtin_amdgcn_s_setprio(1);                                            \
    MFMA_BLK(fa1, fb1);                                                       \
    __builtin_amdgcn_s_setprio(0);                                            \
    __builtin_amdgcn_s_barrier();                                             \
  }

  // prologue: stage tiles 0,1; prefetch K0 frags of tile 0
  STAGE(0, 0);
  asm volatile("s_waitcnt vmcnt(0)" ::: "memory");
  __builtin_amdgcn_s_barrier();
  bf16x8 pa[4], pb[6], qa[4], qb[6];
  RD_K0(pa, pb, lds);        // buf0, complete
  STAGE(64, 1);              // tile 1 -> buf1, stays in flight into tile 0

  // main: 48 K-tiles. Buffer period 3 x frag ping-pong period 2 = 6.
#pragma unroll 1
  for (int tt = 0; tt < 42; tt += 6) {
    TILE(tt + 0, 0, 1, 2, pa, pb, qa, qb, 1, 1);
    TILE(tt + 1, 1, 2, 0, qa, qb, pa, pb, 1, 1);
    TILE(tt + 2, 2, 0, 1, pa, pb, qa, qb, 1, 1);
    TILE(tt + 3, 0, 1, 2, qa, qb, pa, pb, 1, 1);
    TILE(tt + 4, 1, 2, 0, pa, pb, qa, qb, 1, 1);
    TILE(tt + 5, 2, 0, 1, qa, qb, pa, pb, 1, 1);
  }
  TILE(42, 0, 1, 2, pa, pb, qa, qb, 1, 1);
  TILE(43, 1, 2, 0, qa, qb, pa, pb, 1, 1);
  TILE(44, 2, 0, 1, pa, pb, qa, qb, 1, 1);
  TILE(45, 0, 1, 2, qa, qb, pa, pb, 1, 1);   // stages tile 47 (last)
  TILE(46, 1, 2, 0, pa, pb, qa, qb, 0, 1);   // vmcnt(0) retires stage(47)
  TILE(47, 2, 0, 1, qa, qb, pa, pb, 0, 0);   // nothing outstanding

#undef TILE
#undef MFMA_BLK
#undef RD_K0
#undef RD_K1
#undef STAGE

  // epilogue: C/D layout col = l&15, row = (l>>4)*4 + r
#pragma unroll
  for (int mi = 0; mi < 4; ++mi) {
    const size_t row = m0 + wr * 64 + mi * 16 + lk * 4;
#pragma unroll
    for (int ni = 0; ni < 6; ++ni) {
      const int col = n0 + wc * 96 + ni * 16 + lr;
      const float bias = b2[col];
#pragma unroll
      for (int rr = 0; rr < 4; ++rr) {
        C[(row + rr) * N + col] = acc[mi][ni][rr] + bias;
      }
    }
  }
}

// ---------------- fallback: correct fp32 path if workspace too small --------
__global__ __launch_bounds__(256) void fallback_fused(const float* __restrict__ x,
                                                      const float* __restrict__ phi,
                                                      const float* __restrict__ w1,
                                                      const float* __restrict__ b1,
                                                      const float* __restrict__ w2,
                                                      const float* __restrict__ b2,
                                                      float* __restrict__ out) {
  __shared__ float s_h[FF_DIM];
  __shared__ float s_meas[Q_N];
  const int t = threadIdx.x;
  const size_t m = blockIdx.x;
  if (t < Q_N) s_meas[t] = __cosf(x[m * E_DIM + t] + phi[t]);
  __syncthreads();
  for (int f = t; f < FF_DIM; f += 256) {
    const float4* wr = (const float4*)(w1 + (size_t)f * Q_N);
    float4 a = wr[0], b = wr[1];
    float acc = b1[f];
    acc = fmaf(s_meas[0], a.x, acc); acc = fmaf(s_meas[1], a.y, acc);
    acc = fmaf(s_meas[2], a.z, acc); acc = fmaf(s_meas[3], a.w, acc);
    acc = fmaf(s_meas[4], b.x, acc); acc = fmaf(s_meas[5], b.y, acc);
    acc = fmaf(s_meas[6], b.z, acc); acc = fmaf(s_meas[7], b.w, acc);
    s_h[f] = fmaxf(acc, 0.f);
  }
  __syncthreads();
  for (int e = t; e < E_DIM; e += 256) {
    const float* w2r = w2 + (size_t)e * FF_DIM;
    float acc = b2[e];
    for (int f = 0; f < FF_DIM; f += 4) {
      float4 wv = *(const float4*)(w2r + f);
      acc = fmaf(s_h[f + 0], wv.x, acc);
      acc = fmaf(s_h[f + 1], wv.y, acc);
      acc = fmaf(s_h[f + 2], wv.z, acc);
      acc = fmaf(s_h[f + 3], wv.w, acc);
    }
    out[m * E_DIM + e] = acc;
  }
}

extern "C" void kernel_launch(void* const* d_in, const int* in_sizes, int n_in,
                              void* d_out, int out_size, void* d_ws, size_t ws_size,
                              hipStream_t stream) {
  const float* x   = (const float*)d_in[0];
  const float* phi = (const float*)d_in[1];
  const float* w1  = (const float*)d_in[2];
  const float* b1  = (const float*)d_in[3];
  const float* w2  = (const float*)d_in[4];
  const float* b2  = (const float*)d_in[5];
  float* out = (float*)d_out;

  const size_t H_BYTES   = (size_t)M_TOK * FF_DIM * 2;   // 100,663,296
  const size_t W2B_BYTES = (size_t)E_DIM * FF_DIM * 2;   // 4,718,592
  const size_t NEED = H_BYTES + W2B_BYTES;

  if (ws_size >= NEED) {
    __hip_bfloat16* h   = (__hip_bfloat16*)d_ws;
    __hip_bfloat16* w2b = (__hip_bfloat16*)((char*)d_ws + H_BYTES);
    cvt_w2<<<(E_DIM * FF_DIM) / (256 * 4), 256, 0, stream>>>(w2, w2b);
    compute_h<<<(M_TOK / 32) * (FF_DIM / 512), 256, 0, stream>>>(x, phi, w1, b1, h);
    // BM=128, BN=192 -> 128*4 = 512 workgroups (matches in-kernel swizzle)
    gemm_bt<<<(M_TOK / 128) * (E_DIM / 192), 256, 0, stream>>>(h, w2b, b2, out);
  } else {
    fallback_fused<<<M_TOK, 256, 0, stream>>>(x, phi, w1, b1, w2, b2, out);
  }
}

// Round 9
// 108.074 us; speedup vs baseline: 1.0470x; 1.0470x over previous
//
#include <hip/hip_runtime.h>
#include <hip/hip_bf16.h>
#include <stdint.h>

// Problem constants
#define M_TOK 16384   // B*S = 8*2048
#define E_DIM 768
#define FF_DIM 3072
#define Q_N 8

typedef __attribute__((ext_vector_type(8))) short bf16x8;
typedef __attribute__((ext_vector_type(4))) float f32x4;

__device__ inline unsigned short f2bf(float f) {
  union { float f; unsigned u; } v; v.f = f;
  unsigned r = v.u + 0x7fffu + ((v.u >> 16) & 1u);  // round-to-nearest-even
  return (unsigned short)(r >> 16);
}

// ---------------- kernel 0: w2 fp32 -> bf16 ----------------
__global__ __launch_bounds__(256) void cvt_w2(const float* __restrict__ w2,
                                              __hip_bfloat16* __restrict__ w2b) {
  int i = (blockIdx.x * 256 + threadIdx.x) * 4;
  const int n = E_DIM * FF_DIM;
  if (i < n) {
    float4 v = *(const float4*)(w2 + i);
    ushort4 o;
    o.x = f2bf(v.x); o.y = f2bf(v.y); o.z = f2bf(v.z); o.w = f2bf(v.w);
    *(ushort4*)((unsigned short*)w2b + i) = o;
  }
}

// ---------------- kernel 1: h = relu(cos(x[:, :8]+phi) @ w1^T + b1), bf16 ----
__global__ __launch_bounds__(256) void compute_h(const float* __restrict__ x,
                                                 const float* __restrict__ phi,
                                                 const float* __restrict__ w1,
                                                 const float* __restrict__ b1,
                                                 __hip_bfloat16* __restrict__ hout) {
  __shared__ float s_meas[32][8];
  const int t = threadIdx.x;
  const int bm = blockIdx.x / 6;
  const int bf = blockIdx.x % 6;
  const int m0 = bm * 32;
  const int f0 = bf * 512;

  if (t < 64) {
    int m = t >> 1, hh = t & 1;
    float4 v = *(const float4*)(x + (size_t)(m0 + m) * E_DIM + hh * 4);
    float4 p = *(const float4*)(phi + hh * 4);
    s_meas[m][hh * 4 + 0] = __cosf(v.x + p.x);
    s_meas[m][hh * 4 + 1] = __cosf(v.y + p.y);
    s_meas[m][hh * 4 + 2] = __cosf(v.z + p.z);
    s_meas[m][hh * 4 + 3] = __cosf(v.w + p.w);
  }
  __syncthreads();

  const float4* wr = (const float4*)(w1 + (size_t)(f0 + 2 * t) * Q_N);
  float4 a0 = wr[0], a1 = wr[1], b0 = wr[2], b1v = wr[3];
  float wA[8] = {a0.x, a0.y, a0.z, a0.w, a1.x, a1.y, a1.z, a1.w};
  float wB[8] = {b0.x, b0.y, b0.z, b0.w, b1v.x, b1v.y, b1v.z, b1v.w};
  const float biasA = b1[f0 + 2 * t];
  const float biasB = b1[f0 + 2 * t + 1];

  uint32_t* dst32 = (uint32_t*)hout;
  for (int m = 0; m < 32; ++m) {
    float a = biasA, b = biasB;
#pragma unroll
    for (int q = 0; q < 8; ++q) {
      float mv = s_meas[m][q];
      a = fmaf(mv, wA[q], a);
      b = fmaf(mv, wB[q], b);
    }
    a = fmaxf(a, 0.f);
    b = fmaxf(b, 0.f);
    uint32_t pack = (uint32_t)f2bf(a) | ((uint32_t)f2bf(b) << 16);
    dst32[(size_t)(m0 + m) * (FF_DIM / 2) + (f0 / 2) + t] = pack;
  }
}

// ---------------- kernel 2: C[M,N] = h[M,K] @ w2b[N,K]^T + b2 ---------------
// R9: TRAFFIC lever. Five schedules (R0/R2/R4/R5/R7) with different LDS
// loads, occupancy, and waits all land at 3550-3700 cyc/tile -> the invariant
// is L2/LLC bytes: staged traffic = 2MNK(1/BM+1/BN). (256,192)=704MB is the
// optimum under grid>=256; (256,256) drops to 604MB (-14%) at grid 64x3=192
// (75% CU). Traffic-bound -> ~61-64us (chip-level pipe, idle CUs free);
// structure-bound -> null (independent blocks, same per-tile time). MFMA
// floor on 192 CUs = 49.6us, not binding. Body = R5's proven k-half TILE:
// 512 thr, 8 waves 2Mx4N -> wave tile 128x64, acc[8][4] (128 VGPR),
// 24 ds_read_b128/thread/tile (r=0.0234, best yet), 1 barrier, vmcnt(0).
// LDS 2 x 64KB = 128KB, 1 blk/CU.
#define GLDS16(g, l)                                                          \
  __builtin_amdgcn_global_load_lds(                                           \
      (const __attribute__((address_space(1))) void*)(g),                     \
      (__attribute__((address_space(3))) void*)(l), 16, 0, 0)

#define BUF_ELEMS 32768   // (256*64 + 256*64) bf16 elems = 64KB
#define B_OFF 16384       // A region: 256*64 elems

__global__ __launch_bounds__(512, 1) void gemm_bt(const __hip_bfloat16* __restrict__ A,
                                                  const __hip_bfloat16* __restrict__ Bw,
                                                  const float* __restrict__ b2,
                                                  float* __restrict__ C) {
  const int K = FF_DIM;   // 3072
  const int N = E_DIM;    // 768

  __shared__ __align__(16) __hip_bfloat16 lds[2 * BUF_ELEMS];  // 128 KiB

  const int t = threadIdx.x;
  // XCD-aware bijective swizzle: nwg = 192, 192 % 8 == 0.
  // swz = (bid&7)*24 + (bid>>3): consecutive swz (bn-siblings, 3 per bm)
  // share the XCD (bid&7 fixed within each 24-chunk).
  const int swz = (blockIdx.x & 7) * 24 + (blockIdx.x >> 3);
  const int bm = swz / 3;         // 0..63
  const int bn = swz % 3;         // 0..2
  const size_t m0 = (size_t)bm * 256;
  const int n0 = bn * 256;

  const int w = t >> 6, l = t & 63;
  const int wr = w >> 2;          // 0..1  (M wave row, 128 rows)
  const int wc = w & 3;           // 0..3  (N wave col, 64 cols)
  const int lr = l & 15;
  const int lk = l >> 4;          // 0..3

  // fragment-read swizzled chunk constants: row&7 == lr&7 for all frag rows
  const int x0 = lk ^ (lr & 7);        // k-half 0 chunk
  const int x1 = x0 ^ 4;               // k-half 1 chunk
  const int baseA = (wr * 128 + lr) * 64;
  const int baseB = B_OFF + (wc * 64 + lr) * 64;
  const int offA0 = baseA + x0 * 8, offA1 = baseA + x1 * 8;
  const int offB0 = baseB + x0 * 8, offB1 = baseB + x1 * 8;

  // staging: span = 64 rows x 128B = 8KB = 512 thr x 16B. dest = t*16B linear.
  // row-in-span rs = t>>3 (0..63), phys chunk pc = t&7, logical lc = pc^(rs&7)
  const int rs = t >> 3;
  const int lc = (t & 7) ^ (rs & 7);
  const __hip_bfloat16* sA[4];
  const __hip_bfloat16* sB[4];
#pragma unroll
  for (int s = 0; s < 4; ++s) sA[s] = A + (m0 + s * 64 + rs) * (size_t)K + lc * 8;
#pragma unroll
  for (int s = 0; s < 4; ++s) sB[s] = Bw + ((size_t)n0 + s * 64 + rs) * K + lc * 8;

  f32x4 acc[8][4] = {};

#define STAGE(K0S, WBUF)                                                      \
  {                                                                           \
    __hip_bfloat16* ld = lds + (WBUF) * BUF_ELEMS + t * 8;                    \
    GLDS16(sA[0] + (K0S), ld);                                                \
    GLDS16(sA[1] + (K0S), ld + 4096);                                         \
    GLDS16(sA[2] + (K0S), ld + 8192);                                         \
    GLDS16(sA[3] + (K0S), ld + 12288);                                        \
    GLDS16(sB[0] + (K0S), ld + 16384);                                        \
    GLDS16(sB[1] + (K0S), ld + 20480);                                        \
    GLDS16(sB[2] + (K0S), ld + 24576);                                        \
    GLDS16(sB[3] + (K0S), ld + 28672);                                        \
  }

#define TILE(KT, RBUF, DO_STAGE)                                              \
  {                                                                           \
    if (DO_STAGE) STAGE(((KT) + 1) * 64, (RBUF) ^ 1);                         \
    const __hip_bfloat16* la = lds + (RBUF) * BUF_ELEMS;                      \
    { /* ---- k-half 0 ---- */                                                \
      bf16x8 fa[8], fb[4];                                                    \
      _Pragma("unroll") for (int mi = 0; mi < 8; ++mi)                        \
          fa[mi] = *(const bf16x8*)(la + offA0 + mi * 1024);                  \
      _Pragma("unroll") for (int ni = 0; ni < 4; ++ni)                        \
          fb[ni] = *(const bf16x8*)(la + offB0 + ni * 1024);                  \
      __builtin_amdgcn_s_setprio(1);                                          \
      _Pragma("unroll") for (int mi = 0; mi < 8; ++mi)                        \
          _Pragma("unroll") for (int ni = 0; ni < 4; ++ni)                    \
              acc[mi][ni] = __builtin_amdgcn_mfma_f32_16x16x32_bf16(          \
                  fa[mi], fb[ni], acc[mi][ni], 0, 0, 0);                      \
      __builtin_amdgcn_s_setprio(0);                                          \
    }                                                                         \
    { /* ---- k-half 1 ---- */                                                \
      bf16x8 fa[8], fb[4];                                                    \
      _Pragma("unroll") for (int mi = 0; mi < 8; ++mi)                        \
          fa[mi] = *(const bf16x8*)(la + offA1 + mi * 1024);                  \
      _Pragma("unroll") for (int ni = 0; ni < 4; ++ni)                        \
          fb[ni] = *(const bf16x8*)(la + offB1 + ni * 1024);                  \
      __builtin_amdgcn_s_setprio(1);                                          \
      _Pragma("unroll") for (int mi = 0; mi < 8; ++mi)                        \
          _Pragma("unroll") for (int ni = 0; ni < 4; ++ni)                    \
              acc[mi][ni] = __builtin_amdgcn_mfma_f32_16x16x32_bf16(          \
                  fa[mi], fb[ni], acc[mi][ni], 0, 0, 0);                      \
      __builtin_amdgcn_s_setprio(0);                                          \
    }                                                                         \
    asm volatile("s_waitcnt vmcnt(0)" ::: "memory");                          \
    __builtin_amdgcn_s_barrier();                                             \
  }

  // prologue: stage tile 0 into buf 0
  STAGE(0, 0);
  asm volatile("s_waitcnt vmcnt(0)" ::: "memory");
  __builtin_amdgcn_s_barrier();

  // main: 48 K-tiles of 64, two per iteration (static buffers)
#pragma unroll 1
  for (int tt = 0; tt < 46; tt += 2) {
    TILE(tt + 0, 0, 1);
    TILE(tt + 1, 1, 1);
  }
  TILE(46, 0, 1);
  TILE(47, 1, 0);

#undef TILE
#undef STAGE

  // epilogue: C/D layout col = l&15, row = (l>>4)*4 + r
#pragma unroll
  for (int mi = 0; mi < 8; ++mi) {
    const size_t row = m0 + wr * 128 + mi * 16 + lk * 4;
#pragma unroll
    for (int ni = 0; ni < 4; ++ni) {
      const int col = n0 + wc * 64 + ni * 16 + lr;
      const float bias = b2[col];
#pragma unroll
      for (int rr = 0; rr < 4; ++rr) {
        C[(row + rr) * N + col] = acc[mi][ni][rr] + bias;
      }
    }
  }
}

// ---------------- fallback: correct fp32 path if workspace too small --------
__global__ __launch_bounds__(256) void fallback_fused(const float* __restrict__ x,
                                                      const float* __restrict__ phi,
                                                      const float* __restrict__ w1,
                                                      const float* __restrict__ b1,
                                                      const float* __restrict__ w2,
                                                      const float* __restrict__ b2,
                                                      float* __restrict__ out) {
  __shared__ float s_h[FF_DIM];
  __shared__ float s_meas[Q_N];
  const int t = threadIdx.x;
  const size_t m = blockIdx.x;
  if (t < Q_N) s_meas[t] = __cosf(x[m * E_DIM + t] + phi[t]);
  __syncthreads();
  for (int f = t; f < FF_DIM; f += 256) {
    const float4* wr = (const float4*)(w1 + (size_t)f * Q_N);
    float4 a = wr[0], b = wr[1];
    float acc = b1[f];
    acc = fmaf(s_meas[0], a.x, acc); acc = fmaf(s_meas[1], a.y, acc);
    acc = fmaf(s_meas[2], a.z, acc); acc = fmaf(s_meas[3], a.w, acc);
    acc = fmaf(s_meas[4], b.x, acc); acc = fmaf(s_meas[5], b.y, acc);
    acc = fmaf(s_meas[6], b.z, acc); acc = fmaf(s_meas[7], b.w, acc);
    s_h[f] = fmaxf(acc, 0.f);
  }
  __syncthreads();
  for (int e = t; e < E_DIM; e += 256) {
    const float* w2r = w2 + (size_t)e * FF_DIM;
    float acc = b2[e];
    for (int f = 0; f < FF_DIM; f += 4) {
      float4 wv = *(const float4*)(w2r + f);
      acc = fmaf(s_h[f + 0], wv.x, acc);
      acc = fmaf(s_h[f + 1], wv.y, acc);
      acc = fmaf(s_h[f + 2], wv.z, acc);
      acc = fmaf(s_h[f + 3], wv.w, acc);
    }
    out[m * E_DIM + e] = acc;
  }
}

extern "C" void kernel_launch(void* const* d_in, const int* in_sizes, int n_in,
                              void* d_out, int out_size, void* d_ws, size_t ws_size,
                              hipStream_t stream) {
  const float* x   = (const float*)d_in[0];
  const float* phi = (const float*)d_in[1];
  const float* w1  = (const float*)d_in[2];
  const float* b1  = (const float*)d_in[3];
  const float* w2  = (const float*)d_in[4];
  const float* b2  = (const float*)d_in[5];
  float* out = (float*)d_out;

  const size_t H_BYTES   = (size_t)M_TOK * FF_DIM * 2;   // 100,663,296
  const size_t W2B_BYTES = (size_t)E_DIM * FF_DIM * 2;   // 4,718,592
  const size_t NEED = H_BYTES + W2B_BYTES;

  if (ws_size >= NEED) {
    __hip_bfloat16* h   = (__hip_bfloat16*)d_ws;
    __hip_bfloat16* w2b = (__hip_bfloat16*)((char*)d_ws + H_BYTES);
    cvt_w2<<<(E_DIM * FF_DIM) / (256 * 4), 256, 0, stream>>>(w2, w2b);
    compute_h<<<(M_TOK / 32) * (FF_DIM / 512), 256, 0, stream>>>(x, phi, w1, b1, h);
    // BM=256, BN=256 -> 64*3 = 192 workgroups (matches in-kernel swizzle)
    gemm_bt<<<(M_TOK / 256) * (E_DIM / 256), 512, 0, stream>>>(h, w2b, b2, out);
  } else {
    fallback_fused<<<M_TOK, 256, 0, stream>>>(x, phi, w1, b1, w2, b2, out);
  }
}

// Round 10
// 103.573 us; speedup vs baseline: 1.0925x; 1.0435x over previous
//
#include <hip/hip_runtime.h>
#include <hip/hip_bf16.h>
#include <stdint.h>

// Problem constants
#define M_TOK 16384   // B*S = 8*2048
#define E_DIM 768
#define FF_DIM 3072
#define Q_N 8

typedef __attribute__((ext_vector_type(8))) short bf16x8;
typedef __attribute__((ext_vector_type(4))) float f32x4;

__device__ inline unsigned short f2bf(float f) {
  union { float f; unsigned u; } v; v.f = f;
  unsigned r = v.u + 0x7fffu + ((v.u >> 16) & 1u);  // round-to-nearest-even
  return (unsigned short)(r >> 16);
}

// ---------------- kernel 0: w2 fp32 -> FRAGMENT-LINEAR bf16 ----------------
// w2f frag id fid = (kt*2+kh)*48 + nt  (kt: K/64 tile, kh: k-half, nt: n/16).
// Frag = 64 lanes x 8 bf16 (1KB): lane l holds
//   w2[col = nt*16 + (l&15)][k = kt*64 + kh*32 + (l>>4)*8 + j], j=0..7
// — exactly the mfma_16x16x32 B-operand register layout, so the GEMM loads
// B frags with ONE coalesced global_load_dwordx4 (lane offset l*16B).
__global__ __launch_bounds__(256) void cvt_w2f(const float* __restrict__ w2,
                                               __hip_bfloat16* __restrict__ w2f) {
  const int tid = blockIdx.x * 256 + threadIdx.x;   // 0 .. 294911
  const int l = tid & 63;
  const int fid = tid >> 6;          // 0 .. 4607
  const int nt = fid % 48;
  const int kth = fid / 48;          // 0 .. 95  (= kt*2 + kh)
  const int col = nt * 16 + (l & 15);
  const int k0 = kth * 32 + ((l >> 4) << 3);
  const float* src = w2 + (size_t)col * FF_DIM + k0;
  float4 v0 = *(const float4*)(src);
  float4 v1 = *(const float4*)(src + 4);
  uint4 o;
  o.x = (uint32_t)f2bf(v0.x) | ((uint32_t)f2bf(v0.y) << 16);
  o.y = (uint32_t)f2bf(v0.z) | ((uint32_t)f2bf(v0.w) << 16);
  o.z = (uint32_t)f2bf(v1.x) | ((uint32_t)f2bf(v1.y) << 16);
  o.w = (uint32_t)f2bf(v1.z) | ((uint32_t)f2bf(v1.w) << 16);
  *(uint4*)((unsigned short*)w2f + (size_t)tid * 8) = o;
}

// ---------------- kernel 1: h = relu(cos(x[:, :8]+phi) @ w1^T + b1), bf16 ----
__global__ __launch_bounds__(256) void compute_h(const float* __restrict__ x,
                                                 const float* __restrict__ phi,
                                                 const float* __restrict__ w1,
                                                 const float* __restrict__ b1,
                                                 __hip_bfloat16* __restrict__ hout) {
  __shared__ float s_meas[32][8];
  const int t = threadIdx.x;
  const int bm = blockIdx.x / 6;
  const int bf = blockIdx.x % 6;
  const int m0 = bm * 32;
  const int f0 = bf * 512;

  if (t < 64) {
    int m = t >> 1, hh = t & 1;
    float4 v = *(const float4*)(x + (size_t)(m0 + m) * E_DIM + hh * 4);
    float4 p = *(const float4*)(phi + hh * 4);
    s_meas[m][hh * 4 + 0] = __cosf(v.x + p.x);
    s_meas[m][hh * 4 + 1] = __cosf(v.y + p.y);
    s_meas[m][hh * 4 + 2] = __cosf(v.z + p.z);
    s_meas[m][hh * 4 + 3] = __cosf(v.w + p.w);
  }
  __syncthreads();

  const float4* wr = (const float4*)(w1 + (size_t)(f0 + 2 * t) * Q_N);
  float4 a0 = wr[0], a1 = wr[1], b0 = wr[2], b1v = wr[3];
  float wA[8] = {a0.x, a0.y, a0.z, a0.w, a1.x, a1.y, a1.z, a1.w};
  float wB[8] = {b0.x, b0.y, b0.z, b0.w, b1v.x, b1v.y, b1v.z, b1v.w};
  const float biasA = b1[f0 + 2 * t];
  const float biasB = b1[f0 + 2 * t + 1];

  uint32_t* dst32 = (uint32_t*)hout;
  for (int m = 0; m < 32; ++m) {
    float a = biasA, b = biasB;
#pragma unroll
    for (int q = 0; q < 8; ++q) {
      float mv = s_meas[m][q];
      a = fmaf(mv, wA[q], a);
      b = fmaf(mv, wB[q], b);
    }
    a = fmaxf(a, 0.f);
    b = fmaxf(b, 0.f);
    uint32_t pack = (uint32_t)f2bf(a) | ((uint32_t)f2bf(b) << 16);
    dst32[(size_t)(m0 + m) * (FF_DIM / 2) + (f0 / 2) + t] = pack;
  }
}

// ---------------- kernel 2: C[M,N] = h[M,K] @ w2f(frag)^T + b2 --------------
// R10: PIPE-SPLIT. Serial model (fits R0/R4/R5/R7/R9 <8%): tile time =
// LDS-bytes/85 + FLOP/4062, both operands on the LDS pipe. Fix: B comes
// straight from global as register fragments (w2f frag-linear, coalesced
// dwordx4, compiler-counted vmcnt, software-pipelined 1 tile ahead, ZERO
// barriers/LDS involvement — AITER s02 structure). A stays GLDS16->LDS.
// LDS drops to 2x16KB=32KB -> 2 blocks/CU. Waves 1Mx4N (wave 128x48,
// acc[8][3]): per-CU-tile LDS 160KB/85=1880, VMEM 80KB/56=1430, MFMA 1549
// -> bound ~1880 vs serial 3580. Manual vmcnt(6) ONLY for the 4 GLDS16
// (issue-order pinned by sched_barrier(0) so the count is exact; 6 = the
// 6 B-frag loads of t+1 that stay in flight across the barrier).
#define GLDS16(g, l)                                                          \
  __builtin_amdgcn_global_load_lds(                                           \
      (const __attribute__((address_space(1))) void*)(g),                     \
      (__attribute__((address_space(3))) void*)(l), 16, 0, 0)

#define A_ELEMS 8192      // 128*64 bf16 = 16KB per buffer

__global__ __launch_bounds__(256, 2) void gemm_bt(const __hip_bfloat16* __restrict__ A,
                                                  const __hip_bfloat16* __restrict__ w2f,
                                                  const float* __restrict__ b2,
                                                  float* __restrict__ C) {
  const int K = FF_DIM;   // 3072
  const int N = E_DIM;    // 768

  __shared__ __align__(16) __hip_bfloat16 lds[2 * A_ELEMS];  // 32 KiB

  const int t = threadIdx.x;
  // XCD-aware bijective swizzle: nwg = 512, 512 % 8 == 0.
  const int swz = (blockIdx.x & 7) * 64 + (blockIdx.x >> 3);
  const int bm = swz >> 2;        // 0..127
  const int bn = swz & 3;         // 0..3
  const size_t m0 = (size_t)bm * 128;
  const int n0 = bn * 192;

  const int wc = t >> 6;          // 0..3 (N wave col, 48 cols each; all waves
  const int l = t & 63;           //       share the full 128 M rows)
  const int lr = l & 15;
  const int lk = l >> 4;          // 0..3

  // A fragment-read swizzled chunk constants (row&7 == lr&7 for frag rows)
  const int x0 = lk ^ (lr & 7);        // k-half 0 chunk
  const int x1 = x0 ^ 4;               // k-half 1 chunk
  const int offA0 = lr * 64 + x0 * 8;
  const int offA1 = lr * 64 + x1 * 8;

  // A staging: span = 32 rows x 128B = 4KB = 256 thr x 16B, dest linear.
  const int rs = t >> 3;
  const int lc = (t & 7) ^ (rs & 7);
  const __hip_bfloat16* sA[4];
#pragma unroll
  for (int s = 0; s < 4; ++s) sA[s] = A + (m0 + s * 32 + rs) * (size_t)K + lc * 8;

  // B frag base for this wave: frags (nt0 + wc*3 + ni), lane offset l*8 elems.
  // elem addr = (kth*48 + nt)*512 + l*8, kth = kt*2 + kh.
  const __hip_bfloat16* fb = w2f + ((size_t)(bn * 12 + wc * 3)) * 512 + l * 8;

  f32x4 acc[8][3] = {};
  bf16x8 BA[6], BB[6];   // B frags: [kh*3 + ni], current / next tile

#define STAGE_A(K0S, WBUF)                                                    \
  {                                                                           \
    __hip_bfloat16* ld = lds + (WBUF) * A_ELEMS + t * 8;                      \
    GLDS16(sA[0] + (K0S), ld);                                                \
    GLDS16(sA[1] + (K0S), ld + 2048);                                         \
    GLDS16(sA[2] + (K0S), ld + 4096);                                         \
    GLDS16(sA[3] + (K0S), ld + 6144);                                         \
  }

#define LOADB(DST, KT)                                                        \
  _Pragma("unroll") for (int j = 0; j < 6; ++j)                               \
      DST[j] = *(const bf16x8*)(fb + ((size_t)((KT) * 2 + (j / 3)) * 24576) + \
                                (j % 3) * 512);

  // TILE(t): consumes A-buf[t&1] + BCUR (loaded last tile); stages A(t+1)
  // and loads BNXT(t+1). vmcnt ledger (issue order pinned by sched_barrier):
  // entering t: outstanding = 6 (B(t) retired by compiler wait at first use).
  // Actually: end of t-1 waited vmcnt(6) -> exactly F(t) 6 outstanding.
  // t issues S(t+1) 4 then F(t+1) 6 -> 16; compiler waits ~vmcnt(10) before
  // kh0 MFMA (retires F(t)); end: vmcnt(6) retires S(t+1), leaves F(t+1).
#define TILE(KT, RBUF, BCUR, BNXT, DO_NEXT)                                   \
  {                                                                           \
    if (DO_NEXT) STAGE_A(((KT) + 1) * 64, (RBUF) ^ 1);                        \
    __builtin_amdgcn_sched_barrier(0);                                        \
    if (DO_NEXT) LOADB(BNXT, (KT) + 1);                                       \
    __builtin_amdgcn_sched_barrier(0);                                        \
    const __hip_bfloat16* la = lds + (RBUF) * A_ELEMS;                        \
    { /* k-half 0 */                                                          \
      bf16x8 a[8];                                                            \
      _Pragma("unroll") for (int mi = 0; mi < 8; ++mi)                        \
          a[mi] = *(const bf16x8*)(la + offA0 + mi * 1024);                   \
      __builtin_amdgcn_s_setprio(1);                                          \
      _Pragma("unroll") for (int mi = 0; mi < 8; ++mi)                        \
          _Pragma("unroll") for (int ni = 0; ni < 3; ++ni)                    \
              acc[mi][ni] = __builtin_amdgcn_mfma_f32_16x16x32_bf16(          \
                  a[mi], BCUR[ni], acc[mi][ni], 0, 0, 0);                     \
      __builtin_amdgcn_s_setprio(0);                                          \
    }                                                                         \
    { /* k-half 1 */                                                          \
      bf16x8 a[8];                                                            \
      _Pragma("unroll") for (int mi = 0; mi < 8; ++mi)                        \
          a[mi] = *(const bf16x8*)(la + offA1 + mi * 1024);                   \
      __builtin_amdgcn_s_setprio(1);                                          \
      _Pragma("unroll") for (int mi = 0; mi < 8; ++mi)                        \
          _Pragma("unroll") for (int ni = 0; ni < 3; ++ni)                    \
              acc[mi][ni] = __builtin_amdgcn_mfma_f32_16x16x32_bf16(          \
                  a[mi], BCUR[3 + ni], acc[mi][ni], 0, 0, 0);                 \
      __builtin_amdgcn_s_setprio(0);                                          \
    }                                                                         \
    if (DO_NEXT) {                                                            \
      __builtin_amdgcn_sched_barrier(0);                                      \
      asm volatile("s_waitcnt vmcnt(6)" ::: "memory"); /* retire S(t+1) */    \
      __builtin_amdgcn_s_barrier();                                           \
    }                                                                         \
  }

  // prologue: stage A(0), load B(0); vmcnt(6) retires the 4 S-loads (oldest),
  // leaving F(0) in flight (compiler waits at first use).
  STAGE_A(0, 0);
  __builtin_amdgcn_sched_barrier(0);
  LOADB(BA, 0);
  __builtin_amdgcn_sched_barrier(0);
  asm volatile("s_waitcnt vmcnt(6)" ::: "memory");
  __builtin_amdgcn_s_barrier();

  // main: 48 K-tiles, 2 per iteration (B ping-pong BA/BB, A-buf parity t&1)
#pragma unroll 1
  for (int tt = 0; tt < 46; tt += 2) {
    TILE(tt + 0, 0, BA, BB, 1);
    TILE(tt + 1, 1, BB, BA, 1);
  }
  TILE(46, 0, BA, BB, 1);
  TILE(47, 1, BB, BA, 0);

#undef TILE
#undef LOADB
#undef STAGE_A

  // epilogue: C/D layout col = l&15, row = (l>>4)*4 + r
#pragma unroll
  for (int mi = 0; mi < 8; ++mi) {
    const size_t row = m0 + mi * 16 + lk * 4;
#pragma unroll
    for (int ni = 0; ni < 3; ++ni) {
      const int col = n0 + wc * 48 + ni * 16 + lr;
      const float bias = b2[col];
#pragma unroll
      for (int rr = 0; rr < 4; ++rr) {
        C[(row + rr) * N + col] = acc[mi][ni][rr] + bias;
      }
    }
  }
}

// ---------------- fallback: correct fp32 path if workspace too small --------
__global__ __launch_bounds__(256) void fallback_fused(const float* __restrict__ x,
                                                      const float* __restrict__ phi,
                                                      const float* __restrict__ w1,
                                                      const float* __restrict__ b1,
                                                      const float* __restrict__ w2,
                                                      const float* __restrict__ b2,
                                                      float* __restrict__ out) {
  __shared__ float s_h[FF_DIM];
  __shared__ float s_meas[Q_N];
  const int t = threadIdx.x;
  const size_t m = blockIdx.x;
  if (t < Q_N) s_meas[t] = __cosf(x[m * E_DIM + t] + phi[t]);
  __syncthreads();
  for (int f = t; f < FF_DIM; f += 256) {
    const float4* wr = (const float4*)(w1 + (size_t)f * Q_N);
    float4 a = wr[0], b = wr[1];
    float acc = b1[f];
    acc = fmaf(s_meas[0], a.x, acc); acc = fmaf(s_meas[1], a.y, acc);
    acc = fmaf(s_meas[2], a.z, acc); acc = fmaf(s_meas[3], a.w, acc);
    acc = fmaf(s_meas[4], b.x, acc); acc = fmaf(s_meas[5], b.y, acc);
    acc = fmaf(s_meas[6], b.z, acc); acc = fmaf(s_meas[7], b.w, acc);
    s_h[f] = fmaxf(acc, 0.f);
  }
  __syncthreads();
  for (int e = t; e < E_DIM; e += 256) {
    const float* w2r = w2 + (size_t)e * FF_DIM;
    float acc = b2[e];
    for (int f = 0; f < FF_DIM; f += 4) {
      float4 wv = *(const float4*)(w2r + f);
      acc = fmaf(s_h[f + 0], wv.x, acc);
      acc = fmaf(s_h[f + 1], wv.y, acc);
      acc = fmaf(s_h[f + 2], wv.z, acc);
      acc = fmaf(s_h[f + 3], wv.w, acc);
    }
    out[m * E_DIM + e] = acc;
  }
}

extern "C" void kernel_launch(void* const* d_in, const int* in_sizes, int n_in,
                              void* d_out, int out_size, void* d_ws, size_t ws_size,
                              hipStream_t stream) {
  const float* x   = (const float*)d_in[0];
  const float* phi = (const float*)d_in[1];
  const float* w1  = (const float*)d_in[2];
  const float* b1  = (const float*)d_in[3];
  const float* w2  = (const float*)d_in[4];
  const float* b2  = (const float*)d_in[5];
  float* out = (float*)d_out;

  const size_t H_BYTES   = (size_t)M_TOK * FF_DIM * 2;   // 100,663,296
  const size_t W2F_BYTES = (size_t)E_DIM * FF_DIM * 2;   // 4,718,592
  const size_t NEED = H_BYTES + W2F_BYTES;

  if (ws_size >= NEED) {
    __hip_bfloat16* h   = (__hip_bfloat16*)d_ws;
    __hip_bfloat16* w2f = (__hip_bfloat16*)((char*)d_ws + H_BYTES);
    // 96 kth-slices * 48 n-tiles * 64 lanes = 294912 threads / 256 = 1152
    cvt_w2f<<<1152, 256, 0, stream>>>(w2, w2f);
    compute_h<<<(M_TOK / 32) * (FF_DIM / 512), 256, 0, stream>>>(x, phi, w1, b1, h);
    // BM=128, BN=192 -> 128*4 = 512 workgroups (matches in-kernel swizzle)
    gemm_bt<<<(M_TOK / 128) * (E_DIM / 192), 256, 0, stream>>>(h, w2f, b2, out);
  } else {
    fallback_fused<<<M_TOK, 256, 0, stream>>>(x, phi, w1, b1, w2, b2, out);
  }
}